// Round 1
// baseline (143.319 us; speedup 1.0000x reference)
//
#include <hip/hip_runtime.h>
#include <math.h>

#define BB 64
#define NN 8732
#define CC 21

// Monotonic float->uint mapping (total order, handles tiny negative ce from rounding)
static __device__ __forceinline__ unsigned f2u(float f) {
  unsigned u = __float_as_uint(f);
  return (u & 0x80000000u) ? ~u : (u | 0x80000000u);
}

// Kernel 1: per-box map. Computes pos_cond, huber, ce_logits (mining key),
// ce_probs (loss value). Writes keys[B*N], cep[B*N]; accumulates
// loc_sum (acc[0]), positive-conf sum (acc[1]) in double, and per-row pos counts.
__global__ __launch_bounds__(256) void k1_map(
    const float* __restrict__ abd, const float* __restrict__ lbl,
    const float* __restrict__ pbd, const float* __restrict__ plog,
    unsigned* __restrict__ keys, float* __restrict__ cep,
    int* __restrict__ pos_row, double* __restrict__ acc) {
  const int n = blockIdx.x * blockDim.x + threadIdx.x;
  const int b = blockIdx.y;
  const bool valid = n < NN;
  float loc = 0.f, pconf = 0.f;
  int isPos = 0;
  if (valid) {
    const size_t idx = (size_t)b * NN + n;
    const float4 a = reinterpret_cast<const float4*>(abd)[idx];
    const float4 p = reinterpret_cast<const float4*>(pbd)[idx];
    isPos = (a.x != 0.f) || (a.y != 0.f) || (a.z != 0.f) || (a.w != 0.f);

    const float* pr = plog + idx * CC;
    const float* lr = lbl + idx * CC;
    float pv[CC];
    float m = -INFINITY, ssum = 0.f, tdot = 0.f;
#pragma unroll
    for (int j = 0; j < CC; ++j) {
      pv[j] = pr[j];
      m = fmaxf(m, pv[j]);
      ssum += pv[j];
    }
    float es = 0.f;
#pragma unroll
    for (int j = 0; j < CC; ++j) {
      es += expf(pv[j] - m);
      tdot += lr[j] * pv[j];   // = logits[true_class] (labels are exact one-hot)
    }
    // conf CE from "probs": p_t = logits_t / sum(logits), clipped
    float pt = tdot / ssum;
    float ptc = fminf(fmaxf(pt, 1e-7f), 1.0f - 1e-7f);
    float cp = -logf(ptc);
    // CE from logits (hard-negative mining key only)
    float cel = (m + logf(es)) - tdot;
    keys[idx] = isPos ? 0u : f2u(cel);   // positives rank last (reference: -inf)
    cep[idx] = cp;
    pconf = isPos ? cp : 0.f;
    // Huber, mean over 4
    float dx = p.x - a.x, dy = p.y - a.y, dz = p.z - a.z, dw = p.w - a.w;
    float axv = fabsf(dx), ayv = fabsf(dy), azv = fabsf(dz), awv = fabsf(dw);
    float h = (axv <= 1.f ? 0.5f * dx * dx : axv - 0.5f)
            + (ayv <= 1.f ? 0.5f * dy * dy : ayv - 0.5f)
            + (azv <= 1.f ? 0.5f * dz * dz : azv - 0.5f)
            + (awv <= 1.f ? 0.5f * dw * dw : awv - 0.5f);
    loc = isPos ? h * 0.25f : 0.f;
  }
  // wave(64) reduce, then block combine
  float lv = loc, pcf = pconf;
  int pc = isPos;
  for (int off = 32; off > 0; off >>= 1) {
    lv += __shfl_down(lv, off, 64);
    pcf += __shfl_down(pcf, off, 64);
    pc += __shfl_down(pc, off, 64);
  }
  __shared__ float s_l[4], s_p[4];
  __shared__ int s_c[4];
  const int lane = threadIdx.x & 63, wv = threadIdx.x >> 6;
  if (lane == 0) { s_l[wv] = lv; s_p[wv] = pcf; s_c[wv] = pc; }
  __syncthreads();
  if (threadIdx.x == 0) {
    float lt = s_l[0] + s_l[1] + s_l[2] + s_l[3];
    float ptt = s_p[0] + s_p[1] + s_p[2] + s_p[3];
    int ct = s_c[0] + s_c[1] + s_c[2] + s_c[3];
    if (lt != 0.f) atomicAdd(&acc[0], (double)lt);
    if (ptt != 0.f) atomicAdd(&acc[1], (double)ptt);
    if (ct) atomicAdd(&pos_row[b], ct);
  }
}

// Kernel 2: per-row exact radix-select of the k=3*pos hardest negatives
// (descending by key, ties by lowest index), summing their ce_probs into acc[2].
__global__ __launch_bounds__(256) void k2_select(
    const unsigned* __restrict__ keys, const float* __restrict__ cep,
    const int* __restrict__ pos_row, double* __restrict__ acc) {
  __shared__ unsigned sk[NN];       // 34928 B
  __shared__ unsigned hist[256];
  __shared__ unsigned bc[2];
  __shared__ unsigned wtot[4];
  __shared__ double s_d[4];
  const int b = blockIdx.x;
  const int tid = threadIdx.x;
  const int bs = blockDim.x;
  const unsigned k = (unsigned)(pos_row[b] * 3);
  if (k == 0) return;               // uniform per block
  for (int i = tid; i < NN; i += bs) sk[i] = keys[(size_t)b * NN + i];
  __syncthreads();

  // 4-pass 8-bit radix select for the k-th largest key
  unsigned prefix = 0, want = k;
  for (int pass = 0; pass < 4; ++pass) {
    const int shift = 24 - pass * 8;
    const unsigned pmask = (pass == 0) ? 0u : (0xFFFFFFFFu << (shift + 8));
    for (int i = tid; i < 256; i += bs) hist[i] = 0;
    __syncthreads();
    for (int i = tid; i < NN; i += bs) {
      unsigned key = sk[i];
      if ((key & pmask) == prefix)
        atomicAdd(&hist[(key >> shift) & 255u], 1u);
    }
    __syncthreads();
    if (tid == 0) {
      unsigned accum = 0;
      int d = 255;
      for (; d > 0; --d) {
        unsigned c = hist[d];
        if (accum + c >= want) break;
        accum += c;
      }
      bc[0] = prefix | ((unsigned)d << shift);
      bc[1] = want - accum;
    }
    __syncthreads();
    prefix = bc[0];
    want = bc[1];
    __syncthreads();
  }
  const unsigned tau = prefix;      // exact k-th largest key
  const unsigned neq = want;        // how many key==tau to take (lowest index first)

  double mysum = 0.0;
  unsigned base = 0;                // running count of equals seen (index order)
  const int lane = tid & 63, wv = tid >> 6;
  for (int start = 0; start < NN; start += bs) {
    const int i = start + tid;
    const unsigned key = (i < NN) ? sk[i] : 0u;
    const bool gt = (i < NN) && (key > tau);
    const bool eq = (i < NN) && (key == tau);
    if (gt) mysum += (double)cep[(size_t)b * NN + i];
    const unsigned long long mb = __ballot(eq);
    if (lane == 0) wtot[wv] = (unsigned)__popcll(mb);
    __syncthreads();
    unsigned wpref = 0;
#pragma unroll
    for (int w = 0; w < 4; ++w) wpref += (w < wv) ? wtot[w] : 0u;
    const unsigned tot = wtot[0] + wtot[1] + wtot[2] + wtot[3];
    if (eq) {
      const unsigned lanepref =
          (unsigned)__popcll(mb & ((1ull << lane) - 1ull));
      if (base + wpref + lanepref < neq)
        mysum += (double)cep[(size_t)b * NN + i];
    }
    base += tot;
    __syncthreads();
  }
  for (int off = 32; off > 0; off >>= 1) mysum += __shfl_down(mysum, off, 64);
  if (lane == 0) s_d[wv] = mysum;
  __syncthreads();
  if (tid == 0) atomicAdd(&acc[2], s_d[0] + s_d[1] + s_d[2] + s_d[3]);
}

// Kernel 3: finalize the two scalars.
__global__ void k3_final(const double* __restrict__ acc,
                         const int* __restrict__ pos_row,
                         float* __restrict__ out) {
  if (threadIdx.x == 0 && blockIdx.x == 0) {
    long long tp = 0;
    for (int b = 0; b < BB; ++b) tp += pos_row[b];
    const double tot = (tp > 0) ? (double)tp : 1.0;
    out[0] = (float)(acc[0] / tot);
    out[1] = (float)((acc[1] + acc[2]) / tot);
  }
}

extern "C" void kernel_launch(void* const* d_in, const int* in_sizes, int n_in,
                              void* d_out, int out_size, void* d_ws, size_t ws_size,
                              hipStream_t stream) {
  const float* abd = (const float*)d_in[0];   // actual_bbox_deltas [B,N,4]
  const float* lbl = (const float*)d_in[1];   // actual_labels     [B,N,C]
  const float* pbd = (const float*)d_in[2];   // pred_bbox_deltas  [B,N,4]
  const float* plog = (const float*)d_in[3];  // pred_labels       [B,N,C]

  char* ws = (char*)d_ws;
  double* acc = (double*)ws;                        // acc[0]=loc, [1]=pos conf, [2]=neg conf
  int* pos_row = (int*)(ws + 64);                   // [B]
  unsigned* keys = (unsigned*)(ws + 512);           // [B*N]
  float* cep = (float*)(ws + 512 + (size_t)BB * NN * sizeof(unsigned));  // [B*N]

  // accumulators + per-row counts must be zeroed every call (ws is poisoned once)
  hipMemsetAsync(ws, 0, 512, stream);

  dim3 g1((NN + 255) / 256, BB);
  k1_map<<<g1, 256, 0, stream>>>(abd, lbl, pbd, plog, keys, cep, pos_row, acc);
  k2_select<<<BB, 256, 0, stream>>>(keys, cep, pos_row, acc);
  k3_final<<<1, 64, 0, stream>>>(acc, pos_row, (float*)d_out);
}

// Round 2
// 90.113 us; speedup vs baseline: 1.5904x; 1.5904x over previous
//
#include <hip/hip_runtime.h>
#include <math.h>

#define BB 64
#define NN 8732
#define NV4 (NN / 4)  // 2183, row stride 34928 B is 16B-aligned
#define CC 21

// Monotonic float->uint mapping (total order)
static __device__ __forceinline__ unsigned f2u(float f) {
  unsigned u = __float_as_uint(f);
  return (u & 0x80000000u) ? ~u : (u | 0x80000000u);
}

// Kernel 1: per-box map (unchanged from R1 — passed with absmax 0.0).
__global__ __launch_bounds__(256) void k1_map(
    const float* __restrict__ abd, const float* __restrict__ lbl,
    const float* __restrict__ pbd, const float* __restrict__ plog,
    unsigned* __restrict__ keys, float* __restrict__ cep,
    int* __restrict__ pos_row, double* __restrict__ acc) {
  const int n = blockIdx.x * blockDim.x + threadIdx.x;
  const int b = blockIdx.y;
  const bool valid = n < NN;
  float loc = 0.f, pconf = 0.f;
  int isPos = 0;
  if (valid) {
    const size_t idx = (size_t)b * NN + n;
    const float4 a = reinterpret_cast<const float4*>(abd)[idx];
    const float4 p = reinterpret_cast<const float4*>(pbd)[idx];
    isPos = (a.x != 0.f) || (a.y != 0.f) || (a.z != 0.f) || (a.w != 0.f);

    const float* pr = plog + idx * CC;
    const float* lr = lbl + idx * CC;
    float pv[CC];
    float m = -INFINITY, ssum = 0.f, tdot = 0.f;
#pragma unroll
    for (int j = 0; j < CC; ++j) {
      pv[j] = pr[j];
      m = fmaxf(m, pv[j]);
      ssum += pv[j];
    }
    float es = 0.f;
#pragma unroll
    for (int j = 0; j < CC; ++j) {
      es += expf(pv[j] - m);
      tdot += lr[j] * pv[j];  // logits[true_class] (labels exact one-hot)
    }
    float pt = tdot / ssum;
    float ptc = fminf(fmaxf(pt, 1e-7f), 1.0f - 1e-7f);
    float cp = -logf(ptc);
    float cel = (m + logf(es)) - tdot;  // mining key
    keys[idx] = isPos ? 0u : f2u(cel);
    cep[idx] = cp;
    pconf = isPos ? cp : 0.f;
    float dx = p.x - a.x, dy = p.y - a.y, dz = p.z - a.z, dw = p.w - a.w;
    float axv = fabsf(dx), ayv = fabsf(dy), azv = fabsf(dz), awv = fabsf(dw);
    float h = (axv <= 1.f ? 0.5f * dx * dx : axv - 0.5f)
            + (ayv <= 1.f ? 0.5f * dy * dy : ayv - 0.5f)
            + (azv <= 1.f ? 0.5f * dz * dz : azv - 0.5f)
            + (awv <= 1.f ? 0.5f * dw * dw : awv - 0.5f);
    loc = isPos ? h * 0.25f : 0.f;
  }
  float lv = loc, pcf = pconf;
  int pc = isPos;
  for (int off = 32; off > 0; off >>= 1) {
    lv += __shfl_down(lv, off, 64);
    pcf += __shfl_down(pcf, off, 64);
    pc += __shfl_down(pc, off, 64);
  }
  __shared__ float s_l[4], s_p[4];
  __shared__ int s_c[4];
  const int lane = threadIdx.x & 63, wv = threadIdx.x >> 6;
  if (lane == 0) { s_l[wv] = lv; s_p[wv] = pcf; s_c[wv] = pc; }
  __syncthreads();
  if (threadIdx.x == 0) {
    float lt = s_l[0] + s_l[1] + s_l[2] + s_l[3];
    float ptt = s_p[0] + s_p[1] + s_p[2] + s_p[3];
    int ct = s_c[0] + s_c[1] + s_c[2] + s_c[3];
    if (lt != 0.f) atomicAdd(&acc[0], (double)lt);
    if (ptt != 0.f) atomicAdd(&acc[1], (double)ptt);
    if (ct) atomicAdd(&pos_row[b], ct);
  }
}

// Kernel 2 (rewritten): per-row exact radix-select, 1024 threads/row,
// 3 passes (11/11/10 bits), PARALLEL suffix-scan boundary find (the R1
// version's serial tid0 scan was ~50us of latency).
#define K2T 1024
#define K2W 16

__global__ __launch_bounds__(K2T) void k2_select(
    const unsigned* __restrict__ keys, const float* __restrict__ cep,
    const int* __restrict__ pos_row, double* __restrict__ acc) {
  __shared__ unsigned hist[2048];
  __shared__ unsigned wsum[K2W];
  __shared__ unsigned bc[2];
  __shared__ unsigned wtot[K2W];
  __shared__ double s_d[K2W];
  const int b = blockIdx.x;
  const int tid = threadIdx.x;
  const int lane = tid & 63, wv = tid >> 6;
  const int pos = pos_row[b];
  unsigned k = (unsigned)(pos * 3);
  const unsigned negs = (unsigned)(NN - pos);
  if (k > negs) k = negs;  // reference: neg_mask over negatives only
  if (k == 0) return;
  const unsigned* rk = keys + (size_t)b * NN;
  const uint4* rk4 = reinterpret_cast<const uint4*>(rk);

  unsigned want = k;
  unsigned prefix = 0;
  for (int pass = 0; pass < 3; ++pass) {
    const int nb = (pass == 2) ? 1024 : 2048;
    const int shift = (pass == 0) ? 21 : (pass == 1) ? 10 : 0;
    for (int i = tid; i < nb; i += K2T) hist[i] = 0;
    __syncthreads();
    if (pass == 0) {
      for (int t = tid; t < NV4; t += K2T) {
        uint4 v = rk4[t];
        atomicAdd(&hist[v.x >> 21], 1u);
        atomicAdd(&hist[v.y >> 21], 1u);
        atomicAdd(&hist[v.z >> 21], 1u);
        atomicAdd(&hist[v.w >> 21], 1u);
      }
    } else {
      const unsigned pshift = (pass == 1) ? 21u : 10u;
      const unsigned msk = (unsigned)(nb - 1);
      for (int t = tid; t < NV4; t += K2T) {
        uint4 v = rk4[t];
        if ((v.x >> pshift) == prefix) atomicAdd(&hist[(v.x >> shift) & msk], 1u);
        if ((v.y >> pshift) == prefix) atomicAdd(&hist[(v.y >> shift) & msk], 1u);
        if ((v.z >> pshift) == prefix) atomicAdd(&hist[(v.z >> shift) & msk], 1u);
        if ((v.w >> pshift) == prefix) atomicAdd(&hist[(v.w >> shift) & msk], 1u);
      }
    }
    __syncthreads();
    // Parallel suffix-sum boundary find: r-order reverses bins so suffix
    // sum becomes an inclusive prefix scan. PR bins per thread (2 or 1).
    const int PR = nb / K2T;
    unsigned v0, v1 = 0, ls;
    if (PR == 2) {
      v0 = hist[nb - 1 - (tid * 2)];
      v1 = hist[nb - 1 - (tid * 2 + 1)];
      ls = v0 + v1;
    } else {
      v0 = hist[nb - 1 - tid];
      ls = v0;
    }
    unsigned x = ls;
#pragma unroll
    for (int off = 1; off < 64; off <<= 1) {
      unsigned y = __shfl_up(x, off, 64);
      if (lane >= off) x += y;
    }
    if (lane == 63) wsum[wv] = x;
    __syncthreads();
    if (wv == 0 && lane < K2W) {
      unsigned wx = wsum[lane];
#pragma unroll
      for (int off = 1; off < K2W; off <<= 1) {
        unsigned wy = __shfl_up(wx, off, K2W);
        if ((lane & (K2W - 1)) >= off) wx += wy;
      }
      wsum[lane] = wx;  // inclusive scan of wave sums
    }
    __syncthreads();
    const unsigned woff = (wv == 0) ? 0u : wsum[wv - 1];
    const unsigned pinc = woff + x;  // inclusive prefix (thread granularity)
    if (PR == 2) {
      const unsigned p0 = pinc - ls + v0;
      const unsigned p1 = pinc;
      if (v0 > 0 && p0 >= want && p0 - v0 < want) { bc[0] = (unsigned)(nb - 1 - tid * 2); bc[1] = want - (p0 - v0); }
      if (v1 > 0 && p1 >= want && p1 - v1 < want) { bc[0] = (unsigned)(nb - 1 - (tid * 2 + 1)); bc[1] = want - (p1 - v1); }
    } else {
      if (v0 > 0 && pinc >= want && pinc - v0 < want) { bc[0] = (unsigned)(nb - 1 - tid); bc[1] = want - (pinc - v0); }
    }
    __syncthreads();
    const unsigned d = bc[0];
    want = bc[1];
    prefix = (pass == 0) ? d : ((prefix << ((pass == 1) ? 11 : 10)) | d);
    __syncthreads();
  }
  const unsigned tau = prefix;  // exact k-th largest key
  const unsigned neq = want;    // # of key==tau to take, lowest index first

  const float* rc = cep + (size_t)b * NN;
  double mysum = 0.0;
  unsigned base = 0;
  for (int start = 0; start < NN; start += K2T) {
    const int i = start + tid;
    const unsigned key = (i < NN) ? rk[i] : 0u;
    const bool gt = (i < NN) && (key > tau);
    const bool eq = (i < NN) && (key == tau);
    if (gt) mysum += (double)rc[i];
    const unsigned long long mb = __ballot(eq);
    if (lane == 0) wtot[wv] = (unsigned)__popcll(mb);
    __syncthreads();
    unsigned wpref = 0, tot = 0;
#pragma unroll
    for (int w = 0; w < K2W; ++w) {
      const unsigned c = wtot[w];
      wpref += (w < wv) ? c : 0u;
      tot += c;
    }
    if (eq) {
      const unsigned lanepref = (unsigned)__popcll(mb & ((1ull << lane) - 1ull));
      if (base + wpref + lanepref < neq) mysum += (double)rc[i];
    }
    base += tot;
    __syncthreads();
  }
  for (int off = 32; off > 0; off >>= 1) mysum += __shfl_down(mysum, off, 64);
  if (lane == 0) s_d[wv] = mysum;
  __syncthreads();
  if (tid == 0) {
    double t = 0;
#pragma unroll
    for (int w = 0; w < K2W; ++w) t += s_d[w];
    atomicAdd(&acc[2], t);
  }
}

// Kernel 3: finalize the two scalars.
__global__ void k3_final(const double* __restrict__ acc,
                         const int* __restrict__ pos_row,
                         float* __restrict__ out) {
  if (threadIdx.x == 0 && blockIdx.x == 0) {
    long long tp = 0;
    for (int b = 0; b < BB; ++b) tp += pos_row[b];
    const double tot = (tp > 0) ? (double)tp : 1.0;
    out[0] = (float)(acc[0] / tot);
    out[1] = (float)((acc[1] + acc[2]) / tot);
  }
}

extern "C" void kernel_launch(void* const* d_in, const int* in_sizes, int n_in,
                              void* d_out, int out_size, void* d_ws, size_t ws_size,
                              hipStream_t stream) {
  const float* abd = (const float*)d_in[0];
  const float* lbl = (const float*)d_in[1];
  const float* pbd = (const float*)d_in[2];
  const float* plog = (const float*)d_in[3];

  char* ws = (char*)d_ws;
  double* acc = (double*)ws;               // [0]=loc, [1]=pos conf, [2]=neg conf
  int* pos_row = (int*)(ws + 64);          // [B]
  unsigned* keys = (unsigned*)(ws + 512);  // [B*N]
  float* cep = (float*)(ws + 512 + (size_t)BB * NN * sizeof(unsigned));

  hipMemsetAsync(ws, 0, 512, stream);

  dim3 g1((NN + 255) / 256, BB);
  k1_map<<<g1, 256, 0, stream>>>(abd, lbl, pbd, plog, keys, cep, pos_row, acc);
  k2_select<<<BB, K2T, 0, stream>>>(keys, cep, pos_row, acc);
  k3_final<<<1, 64, 0, stream>>>(acc, pos_row, (float*)d_out);
}